// Round 4
// baseline (290.091 us; speedup 1.0000x reference)
//
#include <hip/hip_runtime.h>

// Problem constants: B=4, N=4096, V=4096, P=16, C=16, NK=4, L_MAX=2
#define N_DIM 4096

typedef float v2f __attribute__((ext_vector_type(2)));
typedef float v4f __attribute__((ext_vector_type(4)));

// v_pk_fma_f32 variants (VOP3P).  acc, s, k are 2xf32 register pairs.
// PK_AB  : acc.lo += s.lo*k.lo ; acc.hi += s.lo*k.hi   (broadcast s.lo over k-pair)
// PK_AB_H: acc.lo += s.hi*k.lo ; acc.hi += s.hi*k.hi   (broadcast s.hi over k-pair)
// PK_SB  : acc.lo += s.lo*k.lo ; acc.hi += s.hi*k.lo   (broadcast k.lo over s-pair)
// PK_SB_H: acc.lo += s.lo*k.hi ; acc.hi += s.hi*k.hi   (broadcast k.hi over s-pair)
#define PK_AB(acc, s, k)   asm("v_pk_fma_f32 %0, %1, %2, %0 op_sel:[0,0,0] op_sel_hi:[0,1,1]" : "+v"(acc) : "v"(s), "v"(k))
#define PK_AB_H(acc, s, k) asm("v_pk_fma_f32 %0, %1, %2, %0 op_sel:[1,0,0] op_sel_hi:[1,1,1]" : "+v"(acc) : "v"(s), "v"(k))
#define PK_SB(acc, s, k)   asm("v_pk_fma_f32 %0, %1, %2, %0 op_sel:[0,0,0] op_sel_hi:[1,0,1]" : "+v"(acc) : "v"(s), "v"(k))
#define PK_SB_H(acc, s, k) asm("v_pk_fma_f32 %0, %1, %2, %0 op_sel:[0,1,0] op_sel_hi:[1,1,1]" : "+v"(acc) : "v"(s), "v"(k))

// ---------------------------------------------------------------------------
// Compile-time Clebsch-Gordan coefficients (Racah formula, mirrors reference)
// ---------------------------------------------------------------------------
constexpr double cfac(int x){ double r=1.0; for(int i=2;i<=x;++i) r*=(double)i; return r; }
constexpr double csqrt_(double x){ double g = x>1.0? x:1.0; for(int i=0;i<200;++i) g=0.5*(g+x/g); return g; }
constexpr double cg_coef(int l,int m,int k,int n,int J,int M){
  if(M != m+n) return 0.0;
  if(n < -k || n > k) return 0.0;
  double pref = (double)(2*J+1)*cfac(l+k-J)*cfac(l-k+J)*cfac(-l+k+J)/cfac(l+k+J+1);
  pref *= cfac(J+M)*cfac(J-M)*cfac(l-m)*cfac(l+m)*cfac(k-n)*cfac(k+n);
  int tlo = 0;
  if(k-J-m > tlo) tlo = k-J-m;
  if(l+n-J > tlo) tlo = l+n-J;
  int thi = l+k-J;
  if(l-m < thi) thi = l-m;
  if(k+n < thi) thi = k+n;
  double s = 0.0;
  for(int t=tlo; t<=thi; ++t){
    double d = cfac(t)*cfac(l+k-J-t)*cfac(l-m-t)*cfac(k+n-t)*cfac(J-k+m+t)*cfac(J-l-n+t);
    s += ((t&1)? -1.0 : 1.0)/d;
  }
  return csqrt_(pref)*s;
}

template<int L_,int K_,int J_> struct QtabT { float a[2*J_+1][2*L_+1]; };
template<int L_,int K_,int J_>
constexpr QtabT<L_,K_,J_> make_q(){
  QtabT<L_,K_,J_> q{};
  for(int M=-J_;M<=J_;++M)
    for(int m=-L_;m<=L_;++m)
      q.a[M+J_][m+L_] = (float)cg_coef(L_,m,K_,M-m,J_,M);
  return q;
}

template<int L_,int K_,int J_,int W_,int CHOFF_>
__device__ __forceinline__ void cg_store(const float (&y)[2*L_+1][2*K_+1],
                                         float* __restrict__ o, size_t bvs, int lane){
  constexpr QtabT<L_,K_,J_> Q = make_q<L_,K_,J_>();
  #pragma unroll
  for(int Mi=0; Mi<2*J_+1; ++Mi){
    float acc = 0.f;
    #pragma unroll
    for(int mi=0; mi<2*L_+1; ++mi){
      const int ni = (Mi-J_) - (mi-L_) + K_;     // CG selection rule n = M-m
      if(ni < 0 || ni > 2*K_) continue;
      acc += Q.a[Mi][mi] * y[mi][ni];
    }
    o[(bvs*(2*J_+1) + (size_t)Mi)*W_ + CHOFF_ + lane] = acc;
  }
}

// ---------------------------------------------------------------------------
// 256 threads = 4 waves per (b,v). Wave w owns disjoint (l,k) pairs:
//   w0: (2,2)   w1: (0,2),(1,2)   w2: (1,1),(2,1)   w3: (0,0),(1,0),(2,0),(0,1)
// Lane: n = lane>>4, c = lane&15.
// sig_lds[p][c][m0..8] stride 196/p, 12/c  (m contiguous -> b128 reads, pk pairs)
// kern_t [p][n][kd0..8] stride 48/p, 12/n  (kd contiguous)
// ---------------------------------------------------------------------------
__global__ __launch_bounds__(256, 6)
void conv_kernel(const float* __restrict__ sig0, const float* __restrict__ ker0,
                 const float* __restrict__ sig1, const float* __restrict__ ker1,
                 const float* __restrict__ sig2, const float* __restrict__ ker2,
                 const unsigned* __restrict__ pw, float* __restrict__ out){
  __shared__ __align__(16) float sig_lds[16*196];
  __shared__ __align__(16) float kern_t[16*48];

  const int t    = threadIdx.x;
  const int w    = t >> 6;
  const int lane = t & 63;
  const int bv   = blockIdx.x;
  const size_t bvs = (size_t)bv;
  const int n = lane >> 4, c = lane & 15;

  // --- patch indices: wave-redundant (no barrier). int64-vs-int32 detect. ---
  int row = 0;
  {
    const unsigned probe = (lane < 16) ? pw[2*lane + 1] : 0u;
    const unsigned long long nz = __ballot(probe != 0u);
    const size_t s = (nz == 0ull) ? 2 : 1;          // 2 = int64, 1 = int32
    if(lane < 16){
      const size_t e = ((size_t)bv*16 + lane)*2;
      const int pb = (int)pw[(e+0)*s] & 3;
      const int pn = (int)pw[(e+1)*s] & (N_DIM-1);
      row = pb*N_DIM + pn;
    }
  }

  // --- staging ---
  if(w == 3){
    // kernels -> [p][n][12]
    if(lane < 16){
      float4 v = ((const float4*)(ker0 + bvs*64))[lane];
      float* d = &kern_t[lane*48];
      d[0]=v.x; d[12]=v.y; d[24]=v.z; d[36]=v.w;
    }
    if(lane < 48){
      float4 v = ((const float4*)(ker1 + bvs*192))[lane];
      const int p = lane/3, kd = lane%3;
      float* d = &kern_t[p*48 + 1 + kd];
      d[0]=v.x; d[12]=v.y; d[24]=v.z; d[36]=v.w;
    }
    for(int j=lane; j<80; j+=64){
      float4 v = ((const float4*)(ker2 + bvs*320))[j];
      const int p = j/5, kd = j%5;
      float* d = &kern_t[p*48 + 4 + kd];
      d[0]=v.x; d[12]=v.y; d[24]=v.z; d[36]=v.w;
    }
  } else {
    // signal gather: each float4 = (one m, c=4q..4q+3) -> 4 scalar LDS writes
    const int p = lane >> 2, q = lane & 3;
    const size_t ro = (size_t)__shfl(row, p);
    float* dst = sig_lds + p*196 + 48*q;
    const float4* r0 = (const float4*)(sig0 + ro*16);
    const float4* r1 = (const float4*)(sig1 + ro*48);
    const float4* r2 = (const float4*)(sig2 + ro*80);
#define WR4(v, mm) { dst[0*12+(mm)]=v.x; dst[1*12+(mm)]=v.y; dst[2*12+(mm)]=v.z; dst[3*12+(mm)]=v.w; }
    if(w == 0){
      float4 a=r0[q], b=r1[q],    e=r1[q+4];
      WR4(a,0); WR4(b,1); WR4(e,2);
    } else if(w == 1){
      float4 a=r1[q+8], b=r2[q],  e=r2[q+4];
      WR4(a,3); WR4(b,4); WR4(e,5);
    } else {
      float4 a=r2[q+8], b=r2[q+12], e=r2[q+16];
      WR4(a,6); WR4(b,7); WR4(e,8);
    }
#undef WR4
  }
  __syncthreads();

  float* o0 = out;
  float* o1 = out + 3145728;
  float* o2 = out + 22020096;

  if(w == 0){
    // (2,2): y[m4-8][kd4-8]
    v2f yk45[5], yk67[5], c8a={0,0}, c8b={0,0}; float y88=0.f;
    #pragma unroll
    for(int i=0;i<5;++i){ yk45[i]=(v2f){0,0}; yk67[i]=(v2f){0,0}; }
    #pragma unroll
    for(int p=0;p<16;++p){
      const float* sp = sig_lds + p*196 + c*12;
      const float* kp = kern_t  + p*48  + n*12;
      v4f sB = *(const v4f*)(sp+4);  v2f sC = *(const v2f*)(sp+8);
      v4f kB = *(const v4f*)(kp+4);  v2f kC = *(const v2f*)(kp+8);
      v2f s45=sB.xy, s67=sB.zw, k45=kB.xy, k67=kB.zw;
      PK_AB  (yk45[0], s45, k45); PK_AB  (yk67[0], s45, k67);
      PK_AB_H(yk45[1], s45, k45); PK_AB_H(yk67[1], s45, k67);
      PK_AB  (yk45[2], s67, k45); PK_AB  (yk67[2], s67, k67);
      PK_AB_H(yk45[3], s67, k45); PK_AB_H(yk67[3], s67, k67);
      PK_AB  (yk45[4], sC,  k45); PK_AB  (yk67[4], sC,  k67);
      PK_SB  (c8a, s45, kC);      PK_SB  (c8b, s67, kC);
      y88 += sC.x * kC.x;
    }
    float y[5][5];
    #pragma unroll
    for(int i=0;i<5;++i){ y[i][0]=yk45[i].x; y[i][1]=yk45[i].y; y[i][2]=yk67[i].x; y[i][3]=yk67[i].y; }
    y[0][4]=c8a.x; y[1][4]=c8a.y; y[2][4]=c8b.x; y[3][4]=c8b.y; y[4][4]=y88;
    cg_store<2,2,0,192,128>(y, o0, bvs, lane);
    cg_store<2,2,1,384,320>(y, o1, bvs, lane);
    cg_store<2,2,2,384,320>(y, o2, bvs, lane);
  } else if(w == 1){
    // (0,2) + (1,2)
    v2f a45={0,0}, a67={0,0}, b45[3], b67[3], c8a={0,0}, c8b={0,0};
    #pragma unroll
    for(int i=0;i<3;++i){ b45[i]=(v2f){0,0}; b67[i]=(v2f){0,0}; }
    #pragma unroll
    for(int p=0;p<16;++p){
      const float* sp = sig_lds + p*196 + c*12;
      const float* kp = kern_t  + p*48  + n*12;
      v4f sA = *(const v4f*)(sp);
      v4f kB = *(const v4f*)(kp+4);  v2f kC = *(const v2f*)(kp+8);
      v2f s01=sA.xy, s23=sA.zw, k45=kB.xy, k67=kB.zw;
      PK_AB  (a45, s01, k45);     PK_AB  (a67, s01, k67);
      PK_AB_H(b45[0], s01, k45);  PK_AB_H(b67[0], s01, k67);
      PK_AB  (b45[1], s23, k45);  PK_AB  (b67[1], s23, k67);
      PK_AB_H(b45[2], s23, k45);  PK_AB_H(b67[2], s23, k67);
      PK_SB  (c8a, s01, kC);      PK_SB  (c8b, s23, kC);
    }
    float y0[1][5] = {{a45.x, a45.y, a67.x, a67.y, c8a.x}};
    float y1[3][5];
    y1[0][0]=b45[0].x; y1[0][1]=b45[0].y; y1[0][2]=b67[0].x; y1[0][3]=b67[0].y; y1[0][4]=c8a.y;
    y1[1][0]=b45[1].x; y1[1][1]=b45[1].y; y1[1][2]=b67[1].x; y1[1][3]=b67[1].y; y1[1][4]=c8b.x;
    y1[2][0]=b45[2].x; y1[2][1]=b45[2].y; y1[2][2]=b67[2].x; y1[2][3]=b67[2].y; y1[2][4]=c8b.y;
    #pragma unroll
    for(int kd=0;kd<5;++kd) o2[(bvs*5 + kd)*384 + lane] = y0[0][kd];  // (0,2)@0
    cg_store<1,2,1,384,192>(y1, o1, bvs, lane);
    cg_store<1,2,2,384,128>(y1, o2, bvs, lane);
  } else if(w == 2){
    // (1,1) + (2,1): kd1..3
    v2f q1[5], r23[8];
    #pragma unroll
    for(int i=0;i<5;++i) q1[i]=(v2f){0,0};
    #pragma unroll
    for(int i=0;i<8;++i) r23[i]=(v2f){0,0};
    #pragma unroll
    for(int p=0;p<16;++p){
      const float* sp = sig_lds + p*196 + c*12;
      const float* kp = kern_t  + p*48  + n*12;
      v4f sA = *(const v4f*)(sp); v4f sB = *(const v4f*)(sp+4); v2f sC = *(const v2f*)(sp+8);
      v4f kA = *(const v4f*)(kp);
      v2f s01=sA.xy, s23=sA.zw, s45=sB.xy, s67=sB.zw, k01=kA.xy, k23=kA.zw;
      PK_SB_H(q1[0], s01, k01); PK_SB_H(q1[1], s23, k01);
      PK_SB_H(q1[2], s45, k01); PK_SB_H(q1[3], s67, k01);
      PK_SB_H(q1[4], sC,  k01);
      PK_AB_H(r23[0], s01, k23);
      PK_AB  (r23[1], s23, k23); PK_AB_H(r23[2], s23, k23);
      PK_AB  (r23[3], s45, k23); PK_AB_H(r23[4], s45, k23);
      PK_AB  (r23[5], s67, k23); PK_AB_H(r23[6], s67, k23);
      PK_AB  (r23[7], sC,  k23);
    }
    float y11[3][3], y21[5][3];
    y11[0][0]=q1[0].y; y11[0][1]=r23[0].x; y11[0][2]=r23[0].y;
    y11[1][0]=q1[1].x; y11[1][1]=r23[1].x; y11[1][2]=r23[1].y;
    y11[2][0]=q1[1].y; y11[2][1]=r23[2].x; y11[2][2]=r23[2].y;
    y21[0][0]=q1[2].x; y21[0][1]=r23[3].x; y21[0][2]=r23[3].y;
    y21[1][0]=q1[2].y; y21[1][1]=r23[4].x; y21[1][2]=r23[4].y;
    y21[2][0]=q1[3].x; y21[2][1]=r23[5].x; y21[2][2]=r23[5].y;
    y21[3][0]=q1[3].y; y21[3][1]=r23[6].x; y21[3][2]=r23[6].y;
    y21[4][0]=q1[4].x; y21[4][1]=r23[7].x; y21[4][2]=r23[7].y;
    cg_store<1,1,0,192, 64>(y11, o0, bvs, lane);
    cg_store<1,1,1,384,128>(y11, o1, bvs, lane);
    cg_store<1,1,2,384, 64>(y11, o2, bvs, lane);
    cg_store<2,1,1,384,256>(y21, o1, bvs, lane);
    cg_store<2,1,2,384,256>(y21, o2, bvs, lane);
  } else {
    // (0,0),(1,0),(2,0) + (0,1)
    v2f tt[5], u={0,0}; float y01_1=0.f;
    #pragma unroll
    for(int i=0;i<5;++i) tt[i]=(v2f){0,0};
    #pragma unroll
    for(int p=0;p<16;++p){
      const float* sp = sig_lds + p*196 + c*12;
      const float* kp = kern_t  + p*48  + n*12;
      v4f sA = *(const v4f*)(sp); v4f sB = *(const v4f*)(sp+4); v2f sC = *(const v2f*)(sp+8);
      v4f kA = *(const v4f*)(kp);
      v2f s01=sA.xy, s23=sA.zw, s45=sB.xy, s67=sB.zw, k01=kA.xy, k23=kA.zw;
      PK_SB(tt[0], s01, k01); PK_SB(tt[1], s23, k01); PK_SB(tt[2], s45, k01);
      PK_SB(tt[3], s67, k01); PK_SB(tt[4], sC,  k01);
      PK_AB(u, s01, k23);           // (m0*kd2, m0*kd3)
      y01_1 += sA.x * k01.y;        // m0*kd1
    }
    float y10[3][1], y20[5][1];
    const float y00 = tt[0].x;
    y10[0][0]=tt[0].y; y10[1][0]=tt[1].x; y10[2][0]=tt[1].y;
    y20[0][0]=tt[2].x; y20[1][0]=tt[2].y; y20[2][0]=tt[3].x; y20[3][0]=tt[3].y; y20[4][0]=tt[4].x;
    float y01[3] = {y01_1, u.x, u.y};
    o0[bvs*192 + lane] = y00;                                          // (0,0)@0
    #pragma unroll
    for(int kd=0;kd<3;++kd) o1[(bvs*3 + kd)*384 + lane] = y01[kd];     // (0,1)@0
    cg_store<1,0,1,384, 64>(y10, o1, bvs, lane);
    cg_store<2,0,2,384,192>(y20, o2, bvs, lane);
  }
}

extern "C" void kernel_launch(void* const* d_in, const int* in_sizes, int n_in,
                              void* d_out, int out_size, void* d_ws, size_t ws_size,
                              hipStream_t stream) {
  const float *s0=nullptr,*s1=nullptr,*s2=nullptr,*k0=nullptr,*k1=nullptr,*k2=nullptr;
  const void* pidx=nullptr;
  if(n_in >= 7){
    s0=(const float*)d_in[0]; k0=(const float*)d_in[1];
    s1=(const float*)d_in[2]; k1=(const float*)d_in[3];
    s2=(const float*)d_in[4]; k2=(const float*)d_in[5];
    pidx=d_in[6];
  }
  for(int i=0;i<n_in;++i){
    switch(in_sizes[i]){
      case 262144:  s0=(const float*)d_in[i]; break;   // 4*4096*1*16
      case 786432:  s1=(const float*)d_in[i]; break;   // 4*4096*3*16
      case 1310720: s2=(const float*)d_in[i]; break;   // 4*4096*5*16
      case 1048576: k0=(const float*)d_in[i]; break;   // 4*4096*16*1*4
      case 3145728: k1=(const float*)d_in[i]; break;   // 4*4096*16*3*4
      case 5242880: k2=(const float*)d_in[i]; break;   // 4*4096*16*5*4
      case 524288:  pidx=d_in[i]; break;               // 4*4096*16*2
      default: break;
    }
  }

  conv_kernel<<<16384, 256, 0, stream>>>(s0, k0, s1, k1, s2, k2,
                                         (const unsigned*)pidx, (float*)d_out);
}